// Round 18
// baseline (392.816 us; speedup 1.0000x reference)
//
#include <hip/hip_runtime.h>

// Problem constants
#define NB    2048   // n_back (k)
#define NB4   512    // NB/4 in f32x4 units
#define NOUT  2048   // H*W*COUT
#define NDIM  2048   // H*W*CIN

// Output flat offsets (floats) in d_out: [w_u_, b_u_, w_l_, b_l_]
#define OFF_BU  16777216ull
#define OFF_WL  16785408ull
#define OFF_BL  33562624ull

// ws layout (floats): [0,16384) bias partials (2,4,2048); [16384,+576) T
#define WS_T    16384

typedef float f32x2 __attribute__((ext_vector_type(2)));
typedef float f32x4 __attribute__((ext_vector_type(4)));

// T[co*72 + ci*9 + kh*3 + kw] = kern[((kh*3+kw)*8+ci)*8+co]
// -> per co, 72 CONTIGUOUS floats; block-uniform address -> s_load batches
// into the scalar file (round-10 mechanism; round-14: any threadIdx
// dependence here demotes weights to VMEM and destroys the kernel).
__global__ void prep_kernel(const float* __restrict__ kern, float* __restrict__ T) {
    const int i = blockIdx.x * 64 + threadIdx.x;   // 0..575
    if (i < 576) {
        const int kw = i % 3, kh = (i / 3) % 3, ci = (i / 9) % 8, co = i / 72;
        T[i] = kern[((kh * 3 + kw) * 8 + ci) * 8 + co];
    }
}

// r17 structure (1 owned row/thread, batch-9, SGPR weights) with:
//  (a) explicit f32x2 FMA stream -> v_pk_fma_f32 (r17 accounting showed
//      unpacked v_fma issue = 33us of the 45us VALU time);
//  (b) launch_bounds(256,8): VGPR<=64 formalized (compiler chose 44) and
//      8 waves/EU advertised — waves/SIMD halve at VGPR 64/128/256, so 44
//      VGPR supports 8/SIMD; the old (256,3) hint under-advertised.
__global__ __launch_bounds__(256, 8) void conv_back_kernel(
    const float* __restrict__ wu,
    const float* __restrict__ wl,
    const float* __restrict__ Tw,     // (8co, 72) transposed weights
    const float* __restrict__ bias,   // (8)
    float* __restrict__ outbuf,       // full d_out base
    float* __restrict__ bias_ws)      // (2,4,2048) partial bias sums
{
    const int bid = blockIdx.x;            // 0..4095
    const int klo = bid & 7;               // XCD id = k-chunk (k-disjoint)
    const int j   = bid >> 3;              // per-XCD order, 0..511
    const int r   = j & 15;                // owned out row (fastest: halo loc.)
    const int wig = (j >> 4) & 3;          // wi group
    const int sl  = j >> 6;                // 0..7 (t,b)
    const int t = sl >> 2, b = sl & 3;
    const int kl  = threadIdx.x & 63;
    const int sub = threadIdx.x >> 6;      // 0..3
    const int wi  = wig * 4 + sub;         // 0..15, wave-uniform
    const int k4  = klo * 64 + kl;         // f32x4 index over k, 0..511

    const f32x4* __restrict__ in =
        (const f32x4*)(t ? wl : wu) + (size_t)b * NOUT * NB4 + k4;
    f32x4* __restrict__ wout =
        (f32x4*)(outbuf + (t ? OFF_WL : 0)) + (size_t)b * NDIM * NB4 + k4;

    const bool vlo = wi > 0;               // wave-uniform edge masks
    const bool vhi = wi < 15;

    // block-uniform row validity (s: in-row r-1+s, s=0..2)
    bool rv[3];
    rv[0] = (r > 0);
    rv[1] = true;
    rv[2] = (r < 15);

    f32x2 acc[8][2];                       // [ci][k-half], packed pairs
    #pragma unroll
    for (int ci = 0; ci < 8; ++ci) { acc[ci][0] = (f32x2)(0.f); acc[ci][1] = (f32x2)(0.f); }
    f32x4 pb = (f32x4)(0.f);

    #pragma unroll 1
    for (int co = 0; co < 8; ++co) {
        const float* __restrict__ tb = Tw + co * 72;  // block-uniform -> SGPR
        const float bco = bias[co];

        // ---- batched load phase: 9 loads in flight ----
        f32x4 u[3][3];                      // [s][wi-1, wi, wi+1]
        #pragma unroll
        for (int s = 0; s < 3; ++s) {
            if (rv[s]) {                    // block-uniform branch
                const int ho = r - 1 + s;
                const size_t base = (size_t)((ho * 16 + wi) * 8 + co) * NB4;
                u[s][0] = vlo ? in[base - 8 * NB4] : (f32x4)(0.f);
                u[s][1] =       in[base];
                u[s][2] = vhi ? in[base + 8 * NB4] : (f32x4)(0.f);
            } else {
                u[s][0] = (f32x4)(0.f);
                u[s][1] = (f32x4)(0.f);
                u[s][2] = (f32x4)(0.f);
            }
        }

        // owned row center column (in-row ho == r is s=1)
        pb += bco * u[1][1];

        // ---- FMA phase: 144 v2f32 FMAs (-> v_pk_fma_f32) ----
        // in-row ho = r-1+s feeds out row r with kh = 2-s (r7-verified map)
        #pragma unroll
        for (int s = 0; s < 3; ++s) {
            const int kh = 2 - s;
            #pragma unroll
            for (int ci = 0; ci < 8; ++ci)
                #pragma unroll
                for (int kw = 0; kw < 3; ++kw) {
                    const float Kv = tb[ci * 9 + kh * 3 + kw];  // SGPR
                    const f32x2 kv2 = (f32x2)(Kv);              // splat
                    acc[ci][0] += kv2 * u[s][2 - kw].xy;        // dw = 1-kw
                    acc[ci][1] += kv2 * u[s][2 - kw].zw;
                }
        }
    }

    #pragma unroll
    for (int ci = 0; ci < 8; ++ci) {
        f32x4 o;
        o.xy = acc[ci][0];
        o.zw = acc[ci][1];
        wout[(size_t)((r * 16 + wi) * 8 + ci) * NB4] = o;
    }

    // reduce bias partials across the 4 sub-waves (same k4, different wi)
    __shared__ f32x4 red[4][64];
    red[sub][kl] = pb;
    __syncthreads();
    if (sub == 0) {
        f32x4 tot = red[0][kl] + red[1][kl] + red[2][kl] + red[3][kl];
        float* bws = bias_ws + t * 8192 + b * 2048 + 4 * k4;
        atomicAdd(bws + 0, tot.x);
        atomicAdd(bws + 1, tot.y);
        atomicAdd(bws + 2, tot.z);
        atomicAdd(bws + 3, tot.w);
    }
}

// b_out_ = b_in + ws ; 16384 outputs (2 ul * 4 b * 2048 k)
__global__ void bias_finalize(const float* __restrict__ bu,
                              const float* __restrict__ bl,
                              const float* __restrict__ ws,
                              float* __restrict__ out)
{
    const int idx = blockIdx.x * blockDim.x + threadIdx.x;   // 0..16383
    const int ul  = idx >> 13;
    const int r   = idx & 8191;                              // b*2048 + k
    const float* bin = ul ? bl : bu;
    const size_t off = ul ? OFF_BL : OFF_BU;
    out[off + r] = bin[r] + ws[(size_t)ul * 8192 + r];
}

extern "C" void kernel_launch(void* const* d_in, const int* in_sizes, int n_in,
                              void* d_out, int out_size, void* d_ws, size_t ws_size,
                              hipStream_t stream) {
    // inputs: 0=x (unused), 1=kernel, 2=bias, 3=w_out_u, 4=b_out_u, 5=w_out_l, 6=b_out_l
    const float* kern = (const float*)d_in[1];
    const float* bias = (const float*)d_in[2];
    const float* wu   = (const float*)d_in[3];
    const float* bu   = (const float*)d_in[4];
    const float* wl   = (const float*)d_in[5];
    const float* bl   = (const float*)d_in[6];
    float* out = (float*)d_out;
    float* ws  = (float*)d_ws;

    // zero the 64 KB bias-partial region (graph replays re-run this node)
    (void)hipMemsetAsync(ws, 0, 2ull * 4 * NB * sizeof(float), stream);

    prep_kernel<<<9, 64, 0, stream>>>(kern, ws + WS_T);
    conv_back_kernel<<<dim3(4096), dim3(256), 0, stream>>>(wu, wl, ws + WS_T, bias, out, ws);
    bias_finalize<<<64, 256, 0, stream>>>(bu, bl, ws, out);
}

// Round 19
// 80.404 us; speedup vs baseline: 4.8855x; 4.8855x over previous
//
#include <hip/hip_runtime.h>

// Problem constants
#define NB    2048   // n_back (k)
#define NB4   512    // NB/4 in f32x4 units
#define NOUT  2048   // H*W*COUT
#define NDIM  2048   // H*W*CIN

// Output flat offsets (floats) in d_out: [w_u_, b_u_, w_l_, b_l_]
#define OFF_BU  16777216ull
#define OFF_WL  16785408ull
#define OFF_BL  33562624ull

// ws layout (floats): [0,16384) bias partials (2,4,2048); [16384,+576) T
#define WS_T    16384

typedef float f32x2 __attribute__((ext_vector_type(2)));
typedef float f32x4 __attribute__((ext_vector_type(4)));

// T[co*72 + ci*9 + kh*3 + kw] = kern[((kh*3+kw)*8+ci)*8+co]
// -> per co, 72 CONTIGUOUS floats; block-uniform address -> s_load batches
// into the scalar file (round-10 mechanism; round-14: any threadIdx
// dependence here demotes weights to VMEM and destroys the kernel).
__global__ void prep_kernel(const float* __restrict__ kern, float* __restrict__ T) {
    const int i = blockIdx.x * 64 + threadIdx.x;   // 0..575
    if (i < 576) {
        const int kw = i % 3, kh = (i / 3) % 3, ci = (i / 9) % 8, co = i / 72;
        T[i] = kern[((kh * 3 + kw) * 8 + ci) * 8 + co];
    }
}

// EXACT r17 structure (1 owned row/thread, batch-9 loads, SGPR weights,
// launch_bounds(256,3) -> VGPR 44, 82.5us) with ONE change: the FMA
// stream is expressed as v2f32 ops to pattern-match v_pk_fma_f32.
// r18 LESSON: do NOT tighten launch bounds — (256,8) capped VGPR at 32
// and produced 950MB of spill traffic. Caps convert live-set to spills,
// never shrink it.
__global__ __launch_bounds__(256, 3) void conv_back_kernel(
    const float* __restrict__ wu,
    const float* __restrict__ wl,
    const float* __restrict__ Tw,     // (8co, 72) transposed weights
    const float* __restrict__ bias,   // (8)
    float* __restrict__ outbuf,       // full d_out base
    float* __restrict__ bias_ws)      // (2,4,2048) partial bias sums
{
    const int bid = blockIdx.x;            // 0..4095
    const int klo = bid & 7;               // XCD id = k-chunk (k-disjoint)
    const int j   = bid >> 3;              // per-XCD order, 0..511
    const int r   = j & 15;                // owned out row (fastest: halo loc.)
    const int wig = (j >> 4) & 3;          // wi group
    const int sl  = j >> 6;                // 0..7 (t,b)
    const int t = sl >> 2, b = sl & 3;
    const int kl  = threadIdx.x & 63;
    const int sub = threadIdx.x >> 6;      // 0..3
    const int wi  = wig * 4 + sub;         // 0..15, wave-uniform
    const int k4  = klo * 64 + kl;         // f32x4 index over k, 0..511

    const f32x4* __restrict__ in =
        (const f32x4*)(t ? wl : wu) + (size_t)b * NOUT * NB4 + k4;
    f32x4* __restrict__ wout =
        (f32x4*)(outbuf + (t ? OFF_WL : 0)) + (size_t)b * NDIM * NB4 + k4;

    const bool vlo = wi > 0;               // wave-uniform edge masks
    const bool vhi = wi < 15;

    // block-uniform row validity (s: in-row r-1+s, s=0..2)
    bool rv[3];
    rv[0] = (r > 0);
    rv[1] = true;
    rv[2] = (r < 15);

    f32x2 acc[8][2];                       // [ci][k-half]
    #pragma unroll
    for (int ci = 0; ci < 8; ++ci) { acc[ci][0] = (f32x2)(0.f); acc[ci][1] = (f32x2)(0.f); }
    f32x4 pb = (f32x4)(0.f);

    #pragma unroll 1
    for (int co = 0; co < 8; ++co) {
        const float* __restrict__ tb = Tw + co * 72;  // block-uniform -> SGPR
        const float bco = bias[co];

        // ---- batched load phase: 9 loads in flight ----
        f32x4 u[3][3];                      // [s][wi-1, wi, wi+1]
        #pragma unroll
        for (int s = 0; s < 3; ++s) {
            if (rv[s]) {                    // block-uniform branch
                const int ho = r - 1 + s;
                const size_t base = (size_t)((ho * 16 + wi) * 8 + co) * NB4;
                u[s][0] = vlo ? in[base - 8 * NB4] : (f32x4)(0.f);
                u[s][1] =       in[base];
                u[s][2] = vhi ? in[base + 8 * NB4] : (f32x4)(0.f);
            } else {
                u[s][0] = (f32x4)(0.f);
                u[s][1] = (f32x4)(0.f);
                u[s][2] = (f32x4)(0.f);
            }
        }

        // owned row center column (in-row ho == r is s=1)
        pb += bco * u[1][1];

        // ---- FMA phase: 144 v2f32 FMAs (-> v_pk_fma_f32) ----
        // in-row ho = r-1+s feeds out row r with kh = 2-s (r7-verified map)
        #pragma unroll
        for (int s = 0; s < 3; ++s) {
            const int kh = 2 - s;
            #pragma unroll
            for (int ci = 0; ci < 8; ++ci)
                #pragma unroll
                for (int kw = 0; kw < 3; ++kw) {
                    const float Kv = tb[ci * 9 + kh * 3 + kw];  // SGPR
                    const f32x2 kv2 = (f32x2)(Kv);              // splat
                    acc[ci][0] += kv2 * u[s][2 - kw].xy;        // dw = 1-kw
                    acc[ci][1] += kv2 * u[s][2 - kw].zw;
                }
        }
    }

    #pragma unroll
    for (int ci = 0; ci < 8; ++ci) {
        f32x4 o;
        o.xy = acc[ci][0];
        o.zw = acc[ci][1];
        wout[(size_t)((r * 16 + wi) * 8 + ci) * NB4] = o;
    }

    // reduce bias partials across the 4 sub-waves (same k4, different wi)
    __shared__ f32x4 red[4][64];
    red[sub][kl] = pb;
    __syncthreads();
    if (sub == 0) {
        f32x4 tot = red[0][kl] + red[1][kl] + red[2][kl] + red[3][kl];
        float* bws = bias_ws + t * 8192 + b * 2048 + 4 * k4;
        atomicAdd(bws + 0, tot.x);
        atomicAdd(bws + 1, tot.y);
        atomicAdd(bws + 2, tot.z);
        atomicAdd(bws + 3, tot.w);
    }
}

// b_out_ = b_in + ws ; 16384 outputs (2 ul * 4 b * 2048 k)
__global__ void bias_finalize(const float* __restrict__ bu,
                              const float* __restrict__ bl,
                              const float* __restrict__ ws,
                              float* __restrict__ out)
{
    const int idx = blockIdx.x * blockDim.x + threadIdx.x;   // 0..16383
    const int ul  = idx >> 13;
    const int r   = idx & 8191;                              // b*2048 + k
    const float* bin = ul ? bl : bu;
    const size_t off = ul ? OFF_BL : OFF_BU;
    out[off + r] = bin[r] + ws[(size_t)ul * 8192 + r];
}

extern "C" void kernel_launch(void* const* d_in, const int* in_sizes, int n_in,
                              void* d_out, int out_size, void* d_ws, size_t ws_size,
                              hipStream_t stream) {
    // inputs: 0=x (unused), 1=kernel, 2=bias, 3=w_out_u, 4=b_out_u, 5=w_out_l, 6=b_out_l
    const float* kern = (const float*)d_in[1];
    const float* bias = (const float*)d_in[2];
    const float* wu   = (const float*)d_in[3];
    const float* bu   = (const float*)d_in[4];
    const float* wl   = (const float*)d_in[5];
    const float* bl   = (const float*)d_in[6];
    float* out = (float*)d_out;
    float* ws  = (float*)d_ws;

    // zero the 64 KB bias-partial region (graph replays re-run this node)
    (void)hipMemsetAsync(ws, 0, 2ull * 4 * NB * sizeof(float), stream);

    prep_kernel<<<9, 64, 0, stream>>>(kern, ws + WS_T);
    conv_back_kernel<<<dim3(4096), dim3(256), 0, stream>>>(wu, wl, ws + WS_T, bias, out, ws);
    bias_finalize<<<64, 256, 0, stream>>>(bu, bl, ws, out);
}